// Round 7
// baseline (207.040 us; speedup 1.0000x reference)
//
#include <hip/hip_runtime.h>

// Problem constants (from reference)
#define T_TOTAL 1000000
#define NCHUNK  12288     // 4 streams/lane-group x 3 groups x 1024 blocks = 1 wave/SIMD
#define CLEN    82        // 12288*82 = 1,007,616 >= T_TOTAL (even -> clean pair loop)
#define WARM    24        // warm-up steps (discarded); floor observed at every WARM >= 24

// MODEL (validated R0/R17/R19/R20/R21, all <1% in cy/chunk-step):
//   issue cost ~471 cy VALU+trans per chunk-step (invariant, =VALUBusy*wall/steps)
//   raw dep chain ~1550 cy/step; saturated multi-wave configs all pin at
//   237-240 cy/chunk-step, of which ~25-30% is CROSS-WAVE convoy dead time
//   (R21: 2 waves x 2 streams -> 755cy/STEP2 globally idle, VALUBusy 66%).
//   w=1 has zero convoy but dual-stream ILP only fills 53% (R20).
// R22 = the unexplored corner: ALL parallelism as compiler-visible ILP in
// ONE wave. 4 streams/lane-group: round = max(chain 1550, issue 4x~530
// ~2120-2400) -> issue-bound, no convoy, deterministic schedule.
// Wall = 106 rounds x ~2300cy ~= 102us -> ~192 cy/chunk-step (beats 237).
// VGPR: weights shared across streams (72) + 4x18 state + temps ~= 210 < 256.
// Failure reads: FETCH/WRITE balloon -> spill -> revert to 3-stream;
// dur 118-127 @ VALUBusy ~70% -> floor is intra-wave waitcnt, R0 was optimal.
// R16 lesson: NEVER use __launch_bounds__ min-waves arg. Grid sets occupancy.

typedef float v2 __attribute__((ext_vector_type(2)));   // -> v_pk_*_f32

#define L2E  1.44269504088896340736f
#define K2   2.88539008177792681472f   // 2*log2(e)

__device__ __forceinline__ float bperm(int addr4, float v) {
    return __int_as_float(__builtin_amdgcn_ds_bpermute(addr4, __float_as_int(v)));
}
__device__ __forceinline__ v2 pkfma(v2 a, v2 b, v2 c) {
    return __builtin_elementwise_fma(a, b, c);
}

// (64,1): allocator cap 256 VGPR; ~210-reg live set -> no spills expected.
__global__ __launch_bounds__(64, 1) void lstm_chunks(
    const float* __restrict__ inp,    // (T,1,4)
    const float* __restrict__ wih0,   // (20,1)
    const float* __restrict__ whh0,   // (20,5)
    const float* __restrict__ bih0,   // (20,)
    const float* __restrict__ bhh0,   // (20,)
    const float* __restrict__ wih1,   // (20,5)
    const float* __restrict__ whh1,   // (20,5)
    const float* __restrict__ bih1,   // (20,)
    const float* __restrict__ bhh1,   // (20,)
    const float* __restrict__ fc1w,   // (10,20)
    const float* __restrict__ fc1b,   // (10,)
    const float* __restrict__ fc2w,   // (1,10)
    const float* __restrict__ fc2b,   // (1,)
    float* __restrict__ out)          // (T,1,1)
{
    const int lane = threadIdx.x & 63;
    int cw = lane / 20; if (cw > 2) cw = 2;  // lane-group 0..2; lanes 60-63 shadow
    int q  = lane - cw * 20; if (q > 19) q = 19;
    const int b = q / 5;                     // batch channel 0..3
    const int j = q % 5;                     // hidden index 0..4
    const int id = blockIdx.x * 3 + cw;      // 0..3071
    const int chunkA = id;                   // 0..3071   (has chunk 0)
    const int chunkB = id + 3072;            // no clamps needed (interior)
    const int chunkC = id + 6144;            // no clamps needed (interior)
    const int chunkD = id + 9216;            // tail: upper clamp + store guard
    const int base   = cw * 20;

    // ---- cross-lane gather addresses (intra-wave) ----
    int gh[5];
    #pragma unroll
    for (int k = 0; k < 5; ++k) gh[k] = (base + b * 5 + k) * 4;
    const int rd5  = (lane + 5)  * 4;
    const int rd10 = (lane + 10) * 4;

    // ---- packed pre-scaled weights: pairs (i,f)=01, (g,o)=23; rows g*5+j ----
    // scale: i,f,o rows by -log2e; g row by -2log2e (see cellp()).
    v2 W0x01, W0x23, BB001, BB023, BB101, BB123;
    v2 W0h01[5], W0h23[5], W1a01[5], W1a23[5], W1b01[5], W1b23[5];
    {
        const int r0 = j, r1 = 5 + j, r2 = 10 + j, r3 = 15 + j;
        const v2 s01 = v2{-L2E, -L2E};
        const v2 s23 = v2{-K2,  -L2E};
        W0x01 = s01 * v2{wih0[r0], wih0[r1]};
        W0x23 = s23 * v2{wih0[r2], wih0[r3]};
        BB001 = s01 * v2{bih0[r0] + bhh0[r0], bih0[r1] + bhh0[r1]};
        BB023 = s23 * v2{bih0[r2] + bhh0[r2], bih0[r3] + bhh0[r3]};
        BB101 = s01 * v2{bih1[r0] + bhh1[r0], bih1[r1] + bhh1[r1]};
        BB123 = s23 * v2{bih1[r2] + bhh1[r2], bih1[r3] + bhh1[r3]};
        #pragma unroll
        for (int k = 0; k < 5; ++k) {
            W0h01[k] = s01 * v2{whh0[r0 * 5 + k], whh0[r1 * 5 + k]};
            W0h23[k] = s23 * v2{whh0[r2 * 5 + k], whh0[r3 * 5 + k]};
            W1a01[k] = s01 * v2{wih1[r0 * 5 + k], wih1[r1 * 5 + k]};
            W1a23[k] = s23 * v2{wih1[r2 * 5 + k], wih1[r3 * 5 + k]};
            W1b01[k] = s01 * v2{whh1[r0 * 5 + k], whh1[r1 * 5 + k]};
            W1b23[k] = s23 * v2{whh1[r2 * 5 + k], whh1[r3 * 5 + k]};
        }
    }
    // ---- collapsed linear head: out = v . h1cat + s, v = fc2_w @ fc1_w ----
    float vb[5] = {0, 0, 0, 0, 0};
    float sc = fc2b[0];
    #pragma unroll
    for (int m = 0; m < 10; ++m) {
        const float f2 = fc2w[m];
        sc = __builtin_fmaf(f2, fc1b[m], sc);
        #pragma unroll
        for (int k = 0; k < 5; ++k)
            vb[k] = __builtin_fmaf(f2, fc1w[m * 20 + b * 5 + k], vb[k]);
    }

    // ---- per-stream state (C in scaled domain; zero maps to zero) ----
    float C0a = 0.0f, C1a = 0.0f, C0b = 0.0f, C1b = 0.0f;
    float C0c = 0.0f, C1c = 0.0f, C0d = 0.0f, C1d = 0.0f;
    float h0ra[5] = {0, 0, 0, 0, 0}, h0rb[5] = {0, 0, 0, 0, 0};
    float h0rc[5] = {0, 0, 0, 0, 0}, h0rd[5] = {0, 0, 0, 0, 0};
    float h1Aa[5] = {0, 0, 0, 0, 0}, h1Ba[5] = {0, 0, 0, 0, 0};
    float h1Ab[5] = {0, 0, 0, 0, 0}, h1Bb[5] = {0, 0, 0, 0, 0};
    float h1Ac[5] = {0, 0, 0, 0, 0}, h1Bc[5] = {0, 0, 0, 0, 0};
    float h1Ad[5] = {0, 0, 0, 0, 0}, h1Bd[5] = {0, 0, 0, 0, 0};

    int ta = chunkA * CLEN - WARM;   // chunk 0 runs a dummy warm; reset below
    int tb = chunkB * CLEN - WARM;   // 251,880..  interior
    int tc = chunkC * CLEN - WARM;   // 503,784..  interior
    int td = chunkD * CLEN - WARM;   // 755,688..  tail

    // A: lower clamp only (chunk 0 dummy warm); B,C: interior, no clamps;
    // D: upper clamp only (tail).
    auto ldxA = [&](int t_) -> float {
        const int tt = (t_ < 0) ? 0 : t_;
        return inp[(size_t)tt * 4 + b];
    };
    auto ldxI = [&](int t_) -> float {      // interior
        return inp[(size_t)t_ * 4 + b];
    };
    auto ldxD = [&](int t_) -> float {
        const int tt = (t_ > T_TOTAL - 1) ? (T_TOTAL - 1) : t_;
        return inp[(size_t)tt * 4 + b];
    };

    // cell epilogue in pre-scaled domain (identical math to R12)
    auto cellp = [&](v2 A01, v2 A23, float& C) -> float {
        const float ei = __builtin_amdgcn_exp2f(A01.x);
        const float ef = __builtin_amdgcn_exp2f(A01.y);
        const float eg = __builtin_amdgcn_exp2f(A23.x);
        const float eo = __builtin_amdgcn_exp2f(A23.y);
        const float Di = 1.0f + ei, Df = 1.0f + ef, Dg = 1.0f + eg, Do = 1.0f + eo;
        const float p1 = Di * Df, p2 = Dg * Do, p3 = Df * Do;
        const float r  = __builtin_amdgcn_rcpf(p1 * p2);
        const float f  = (Di * p2) * r;                  // 1/Df
        const float o  = (p1 * Dg) * r;                  // 1/Do
        const float tg = __builtin_fmaf(K2, eg, -K2);    // K2*(eg-1)
        C = __builtin_fmaf(f, C, (tg * p3) * r);
        const float eh = __builtin_amdgcn_exp2f(C);
        return (o * (1.0f - eh)) * __builtin_amdgcn_rcpf(1.0f + eh);
    };

    auto matvec0 = [&](float x, const float (&h)[5], v2& A01, v2& A23) {
        const v2 xx = v2{x, x};
        v2 P01 = pkfma(W0x01, xx, BB001);
        v2 P23 = pkfma(W0x23, xx, BB023);
        const v2 k0 = v2{h[0], h[0]}, k1 = v2{h[1], h[1]};
        const v2 k2 = v2{h[2], h[2]}, k3 = v2{h[3], h[3]};
        const v2 k4 = v2{h[4], h[4]};
        P01 = pkfma(W0h01[0], k0, P01);  v2 Q01 = W0h01[2] * k2;
        P23 = pkfma(W0h23[0], k0, P23);  v2 Q23 = W0h23[2] * k2;
        P01 = pkfma(W0h01[1], k1, P01);  Q01 = pkfma(W0h01[3], k3, Q01);
        P23 = pkfma(W0h23[1], k1, P23);  Q23 = pkfma(W0h23[3], k3, Q23);
        Q01 = pkfma(W0h01[4], k4, Q01);
        Q23 = pkfma(W0h23[4], k4, Q23);
        A01 = P01 + Q01; A23 = P23 + Q23;
    };
    auto matvec1 = [&](const float (&h0)[5], const float (&h1)[5], v2& A01, v2& A23) {
        v2 P01 = BB101, P23 = BB123;
        const v2 g0 = v2{h1[0], h1[0]};
        v2 Q01 = W1b01[0] * g0;
        v2 Q23 = W1b23[0] * g0;
        #pragma unroll
        for (int k = 0; k < 5; ++k) {
            const v2 hk = v2{h0[k], h0[k]};
            P01 = pkfma(W1a01[k], hk, P01);
            P23 = pkfma(W1a23[k], hk, P23);
        }
        #pragma unroll
        for (int k = 1; k < 5; ++k) {
            const v2 gk = v2{h1[k], h1[k]};
            Q01 = pkfma(W1b01[k], gk, Q01);
            Q23 = pkfma(W1b23[k], gk, Q23);
        }
        A01 = P01 + Q01; A23 = P23 + Q23;
    };

    float xca, xcb, xcc, xcd;
    // ---- prologue: layer0 first step for all 4 streams, interleaved ----
    {
        v2 Aa01, Aa23, Ab01, Ab23, Ac01, Ac23, Ad01, Ad23;
        matvec0(ldxA(ta), h0ra, Aa01, Aa23);     // h0r* all zeros here
        matvec0(ldxI(tb), h0rb, Ab01, Ab23);
        matvec0(ldxI(tc), h0rc, Ac01, Ac23);
        matvec0(ldxD(td), h0rd, Ad01, Ad23);
        const float h0a = cellp(Aa01, Aa23, C0a);
        const float h0b = cellp(Ab01, Ab23, C0b);
        const float h0c = cellp(Ac01, Ac23, C0c);
        const float h0d = cellp(Ad01, Ad23, C0d);
        #pragma unroll
        for (int k = 0; k < 5; ++k) h0ra[k] = bperm(gh[k], h0a);
        #pragma unroll
        for (int k = 0; k < 5; ++k) h0rb[k] = bperm(gh[k], h0b);
        #pragma unroll
        for (int k = 0; k < 5; ++k) h0rc[k] = bperm(gh[k], h0c);
        #pragma unroll
        for (int k = 0; k < 5; ++k) h0rd[k] = bperm(gh[k], h0d);
        xca = ldxA(ta + 1);
        xcb = ldxI(tb + 1);
        xcc = ldxI(tc + 1);
        xcd = ldxD(td + 1);
    }

    // fused quad-stream step: all 4 streams interleaved per phase; each
    // stream's bperm/trans latency is filled by the other streams' issue.
    // One wave owns the SIMD -> no cross-wave convoy, static schedule.
    #define STEP4(IA, OA, IB, OB, IC, OC, ID, OD, EMIT)                        \
    {                                                                          \
        v2 Aa01, Aa23, Ab01, Ab23, Ac01, Ac23, Ad01, Ad23;                     \
        matvec1(h0ra, IA, Aa01, Aa23);                                         \
        matvec1(h0rb, IB, Ab01, Ab23);                                         \
        matvec1(h0rc, IC, Ac01, Ac23);                                         \
        matvec1(h0rd, ID, Ad01, Ad23);                                         \
        const float h1a = cellp(Aa01, Aa23, C1a);                              \
        const float h1b = cellp(Ab01, Ab23, C1b);                              \
        const float h1c = cellp(Ac01, Ac23, C1c);                              \
        const float h1d = cellp(Ad01, Ad23, C1d);                              \
        _Pragma("unroll")                                                      \
        for (int k = 0; k < 5; ++k) OA[k] = bperm(gh[k], h1a);                 \
        _Pragma("unroll")                                                      \
        for (int k = 0; k < 5; ++k) OB[k] = bperm(gh[k], h1b);                 \
        _Pragma("unroll")                                                      \
        for (int k = 0; k < 5; ++k) OC[k] = bperm(gh[k], h1c);                 \
        _Pragma("unroll")                                                      \
        for (int k = 0; k < 5; ++k) OD[k] = bperm(gh[k], h1d);                 \
        const float xna = ldxA(ta + 2);                                        \
        const float xnb = ldxI(tb + 2);                                        \
        const float xnc = ldxI(tc + 2);                                        \
        const float xnd = ldxD(td + 2);                                        \
        matvec0(xca, h0ra, Aa01, Aa23);                                        \
        matvec0(xcb, h0rb, Ab01, Ab23);                                        \
        matvec0(xcc, h0rc, Ac01, Ac23);                                        \
        matvec0(xcd, h0rd, Ad01, Ad23);                                        \
        const float h0a = cellp(Aa01, Aa23, C0a);                              \
        const float h0b = cellp(Ab01, Ab23, C0b);                              \
        const float h0c = cellp(Ac01, Ac23, C0c);                              \
        const float h0d = cellp(Ad01, Ad23, C0d);                              \
        _Pragma("unroll")                                                      \
        for (int k = 0; k < 5; ++k) h0ra[k] = bperm(gh[k], h0a);               \
        _Pragma("unroll")                                                      \
        for (int k = 0; k < 5; ++k) h0rb[k] = bperm(gh[k], h0b);               \
        _Pragma("unroll")                                                      \
        for (int k = 0; k < 5; ++k) h0rc[k] = bperm(gh[k], h0c);               \
        _Pragma("unroll")                                                      \
        for (int k = 0; k < 5; ++k) h0rd[k] = bperm(gh[k], h0d);               \
        xca = xna; xcb = xnb; xcc = xnc; xcd = xnd;                            \
        if (EMIT) {                                                            \
            float pa = vb[0] * OA[0];                                          \
            pa = __builtin_fmaf(vb[1], OA[1], pa);                             \
            pa = __builtin_fmaf(vb[2], OA[2], pa);                             \
            pa = __builtin_fmaf(vb[3], OA[3], pa);                             \
            pa = __builtin_fmaf(vb[4], OA[4], pa);                             \
            float pb = vb[0] * OB[0];                                          \
            pb = __builtin_fmaf(vb[1], OB[1], pb);                             \
            pb = __builtin_fmaf(vb[2], OB[2], pb);                             \
            pb = __builtin_fmaf(vb[3], OB[3], pb);                             \
            pb = __builtin_fmaf(vb[4], OB[4], pb);                             \
            float pc = vb[0] * OC[0];                                          \
            pc = __builtin_fmaf(vb[1], OC[1], pc);                             \
            pc = __builtin_fmaf(vb[2], OC[2], pc);                             \
            pc = __builtin_fmaf(vb[3], OC[3], pc);                             \
            pc = __builtin_fmaf(vb[4], OC[4], pc);                             \
            float pd = vb[0] * OD[0];                                          \
            pd = __builtin_fmaf(vb[1], OD[1], pd);                             \
            pd = __builtin_fmaf(vb[2], OD[2], pd);                             \
            pd = __builtin_fmaf(vb[3], OD[3], pd);                             \
            pd = __builtin_fmaf(vb[4], OD[4], pd);                             \
            const float ua = pa + bperm(rd5, pa);                              \
            const float ub = pb + bperm(rd5, pb);                              \
            const float uc = pc + bperm(rd5, pc);                              \
            const float ud = pd + bperm(rd5, pd);                              \
            const float Sa = ua + bperm(rd10, ua);                             \
            const float Sb = ub + bperm(rd10, ub);                             \
            const float Sc = uc + bperm(rd10, uc);                             \
            const float Sd = ud + bperm(rd10, ud);                             \
            if (q == 0) {                                                      \
                out[ta] = Sa + sc;                 /* ta < T always */         \
                out[tb] = Sb + sc;                 /* interior */              \
                out[tc] = Sc + sc;                 /* interior */              \
                if (td < T_TOTAL) out[td] = Sd + sc;                           \
            }                                                                  \
        }                                                                      \
        ++ta; ++tb; ++tc; ++td;                                                \
    }

    // ---- warm-up: uniform 24 steps for ALL streams (branch-free, fully
    //      interleaved). chunk 0's A-stream runs a dummy warm on clamped x. ----
    for (int i = 0; i < WARM; i += 2) {
        STEP4(h1Aa, h1Ba, h1Ab, h1Bb, h1Ac, h1Bc, h1Ad, h1Bd, false)
        STEP4(h1Ba, h1Aa, h1Bb, h1Ab, h1Bc, h1Ac, h1Bd, h1Ad, false)
    }

    // ---- chunk 0 exactness: reset its state to zero and redo the 1-step
    //      prologue at t=0 (divergent, 20 lanes, once). ta is already 0. ----
    if (chunkA == 0) {
        C0a = 0.0f; C1a = 0.0f;
        #pragma unroll
        for (int k = 0; k < 5; ++k) { h1Aa[k] = 0.0f; h1Ba[k] = 0.0f; }
        float z[5] = {0, 0, 0, 0, 0};
        v2 A01, A23;
        matvec0(inp[b], z, A01, A23);            // x(0), zero state
        const float h0 = cellp(A01, A23, C0a);
        #pragma unroll
        for (int k = 0; k < 5; ++k) h0ra[k] = bperm(gh[k], h0);  // sources 0..19 active
        xca = inp[4 + b];                        // x(1)
    }

    // ---- output loop: CLEN even -> exactly CLEN/2 ping-pong pairs ----
    for (int i = 0; i < CLEN; i += 2) {
        STEP4(h1Aa, h1Ba, h1Ab, h1Bb, h1Ac, h1Bc, h1Ad, h1Bd, true)
        STEP4(h1Ba, h1Aa, h1Bb, h1Ab, h1Bc, h1Ac, h1Bd, h1Ad, true)
    }

    #undef STEP4
}

extern "C" void kernel_launch(void* const* d_in, const int* in_sizes, int n_in,
                              void* d_out, int out_size, void* d_ws, size_t ws_size,
                              hipStream_t stream) {
    (void)in_sizes; (void)n_in; (void)d_ws; (void)ws_size; (void)out_size;
    lstm_chunks<<<NCHUNK / 12, 64, 0, stream>>>(
        (const float*)d_in[0],  (const float*)d_in[1],  (const float*)d_in[2],
        (const float*)d_in[3],  (const float*)d_in[4],  (const float*)d_in[5],
        (const float*)d_in[6],  (const float*)d_in[7],  (const float*)d_in[8],
        (const float*)d_in[9],  (const float*)d_in[10], (const float*)d_in[11],
        (const float*)d_in[12], (float*)d_out);
}

// Round 8
// 195.936 us; speedup vs baseline: 1.0567x; 1.0567x over previous
//
#include <hip/hip_runtime.h>

// Problem constants (from reference)
#define T_TOTAL 1000000
#define NCHUNK  12288     // 3 chunks/block x 4096 blocks = 4 waves/SIMD
#define CLEN    82        // 12288*82 = 1,007,616 >= T_TOTAL
#define WARM    24        // warm-up steps (discarded); floor observed at every WARM >= 24

// R22 POST-MORTEM -> new roofline identified: ds_bpermute issue rate pins at
// 0.067/cy/CU (~15cy per wave64 crossbar op) in EVERY saturated config
// (R0/R17/R21); latency-bound configs sit below. 12 bperms/wave-step x 15cy
// = 180cy > VALU 154cy -> the permute pipe, not the VALU, set the 237
// cy/chunk-step floor. More waves/streams just queue on it (R22: 4-stream
// ILP -> stall per stream unchanged).
// R23: kill the crossbar. h-broadcast via PADDED LDS slots: 1 ds_write_b32
// + ds_read_b128+b32 per layer (banked, broadcast-read, conflict-spread via
// 68-word cw stride) = 6 cheap ops vs 10 bperms. Head keeps 2 bperms and
// reads h1(t-1) from the regs already loaded for matvec1 -> emit deferred
// one step (out[t-1] at step t; one extra no-emit step per chunk).
// Binding constraint returns to VALU issue (154/chunk-step invariant):
// wall = 107 steps x max(L~1550, 4x~480) ~= 209k cy ~= 87us.
// DECISIVE SIGNAL: VALUBusy -> 80-92% if theory right; ~65% + 125us if not.
// R16 lesson: NEVER use __launch_bounds__ min-waves arg. Grid sets occupancy.
// VGPR must stay <=128 for 4 waves/SIMD.

typedef float v2 __attribute__((ext_vector_type(2)));   // -> v_pk_*_f32
typedef float v4 __attribute__((ext_vector_type(4)));   // -> ds_read_b128

#define L2E  1.44269504088896340736f
#define K2   2.88539008177792681472f   // 2*log2(e)

__device__ __forceinline__ float bperm(int addr4, float v) {
    return __int_as_float(__builtin_amdgcn_ds_bpermute(addr4, __float_as_int(v)));
}
__device__ __forceinline__ v2 pkfma(v2 a, v2 b, v2 c) {
    return __builtin_elementwise_fma(a, b, c);
}

// (64,1): full VGPR budget; ~100-reg live set -> no spills, <=128 for 4 waves.
__global__ __launch_bounds__(64, 1) void lstm_chunks(
    const float* __restrict__ inp,    // (T,1,4)
    const float* __restrict__ wih0,   // (20,1)
    const float* __restrict__ whh0,   // (20,5)
    const float* __restrict__ bih0,   // (20,)
    const float* __restrict__ bhh0,   // (20,)
    const float* __restrict__ wih1,   // (20,5)
    const float* __restrict__ whh1,   // (20,5)
    const float* __restrict__ bih1,   // (20,)
    const float* __restrict__ bhh1,   // (20,)
    const float* __restrict__ fc1w,   // (10,20)
    const float* __restrict__ fc1b,   // (10,)
    const float* __restrict__ fc2w,   // (1,10)
    const float* __restrict__ fc2b,   // (1,)
    float* __restrict__ out)          // (T,1,1)
{
    // h0 slots: word cw*68 + b*8 + k ; h1 slots: +204 words.
    // 68-word cw stride: b128 reads of cw0/cw1 hit disjoint bank quartets
    // ({0,8,16,24}+{0..3} vs +4) -> max 2-way (free). 16B-aligned bases.
    __shared__ float hsh[408];        // 1632 B

    const int lane = threadIdx.x & 63;
    int cw = lane / 20; if (cw > 2) cw = 2;  // lane-group 0..2; lanes 60-63 shadow
    int q  = lane - cw * 20; if (q > 19) q = 19;
    const int b = q / 5;                     // batch channel 0..3
    const int j = q % 5;                     // hidden index 0..4
    const int chunk = blockIdx.x * 3 + cw;   // 0..12287

    const int rw = cw * 68 + b * 8;          // read base word (h0); h1 at +204
    const int ww = rw + j;                   // write word (h0); h1 at +204

    const int rd5  = (lane + 5)  * 4;        // head reduction (2 bperms kept)
    const int rd10 = (lane + 10) * 4;

    // ---- packed pre-scaled weights: pairs (i,f)=01, (g,o)=23; rows g*5+j ----
    // scale: i,f,o rows by -log2e; g row by -2log2e (see cellp()).
    v2 W0x01, W0x23, BB001, BB023, BB101, BB123;
    v2 W0h01[5], W0h23[5], W1a01[5], W1a23[5], W1b01[5], W1b23[5];
    {
        const int r0 = j, r1 = 5 + j, r2 = 10 + j, r3 = 15 + j;
        const v2 s01 = v2{-L2E, -L2E};
        const v2 s23 = v2{-K2,  -L2E};
        W0x01 = s01 * v2{wih0[r0], wih0[r1]};
        W0x23 = s23 * v2{wih0[r2], wih0[r3]};
        BB001 = s01 * v2{bih0[r0] + bhh0[r0], bih0[r1] + bhh0[r1]};
        BB023 = s23 * v2{bih0[r2] + bhh0[r2], bih0[r3] + bhh0[r3]};
        BB101 = s01 * v2{bih1[r0] + bhh1[r0], bih1[r1] + bhh1[r1]};
        BB123 = s23 * v2{bih1[r2] + bhh1[r2], bih1[r3] + bhh1[r3]};
        #pragma unroll
        for (int k = 0; k < 5; ++k) {
            W0h01[k] = s01 * v2{whh0[r0 * 5 + k], whh0[r1 * 5 + k]};
            W0h23[k] = s23 * v2{whh0[r2 * 5 + k], whh0[r3 * 5 + k]};
            W1a01[k] = s01 * v2{wih1[r0 * 5 + k], wih1[r1 * 5 + k]};
            W1a23[k] = s23 * v2{wih1[r2 * 5 + k], wih1[r3 * 5 + k]};
            W1b01[k] = s01 * v2{whh1[r0 * 5 + k], whh1[r1 * 5 + k]};
            W1b23[k] = s23 * v2{whh1[r2 * 5 + k], whh1[r3 * 5 + k]};
        }
    }
    // ---- collapsed linear head: out = v . h1cat + s, v = fc2_w @ fc1_w ----
    float vb[5] = {0, 0, 0, 0, 0};
    float sc = fc2b[0];
    #pragma unroll
    for (int m = 0; m < 10; ++m) {
        const float f2 = fc2w[m];
        sc = __builtin_fmaf(f2, fc1b[m], sc);
        #pragma unroll
        for (int k = 0; k < 5; ++k)
            vb[k] = __builtin_fmaf(f2, fc1w[m * 20 + b * 5 + k], vb[k]);
    }

    // ---- state (C in scaled domain; zero maps to zero) ----
    float C0 = 0.0f, C1 = 0.0f;
    int t = chunk * CLEN - WARM;     // chunk 0 runs a dummy warm; reset below

    auto ldx = [&](int t_) -> float {
        int tt = t_ < 0 ? 0 : t_;                       // chunk-0 dummy warm
        tt = tt > T_TOTAL - 1 ? T_TOTAL - 1 : tt;       // tail chunks
        return inp[(size_t)tt * 4 + b];
    };

    // cell epilogue in pre-scaled domain (identical math to R12)
    auto cellp = [&](v2 A01, v2 A23, float& C) -> float {
        const float ei = __builtin_amdgcn_exp2f(A01.x);
        const float ef = __builtin_amdgcn_exp2f(A01.y);
        const float eg = __builtin_amdgcn_exp2f(A23.x);
        const float eo = __builtin_amdgcn_exp2f(A23.y);
        const float Di = 1.0f + ei, Df = 1.0f + ef, Dg = 1.0f + eg, Do = 1.0f + eo;
        const float p1 = Di * Df, p2 = Dg * Do, p3 = Df * Do;
        const float r  = __builtin_amdgcn_rcpf(p1 * p2);
        const float f  = (Di * p2) * r;                  // 1/Df
        const float o  = (p1 * Dg) * r;                  // 1/Do
        const float tg = __builtin_fmaf(K2, eg, -K2);    // K2*(eg-1)
        C = __builtin_fmaf(f, C, (tg * p3) * r);
        const float eh = __builtin_amdgcn_exp2f(C);
        return (o * (1.0f - eh)) * __builtin_amdgcn_rcpf(1.0f + eh);
    };

    auto matvec0 = [&](float x, const float (&h)[5], v2& A01, v2& A23) {
        const v2 xx = v2{x, x};
        v2 P01 = pkfma(W0x01, xx, BB001);
        v2 P23 = pkfma(W0x23, xx, BB023);
        const v2 k0 = v2{h[0], h[0]}, k1 = v2{h[1], h[1]};
        const v2 k2 = v2{h[2], h[2]}, k3 = v2{h[3], h[3]};
        const v2 k4 = v2{h[4], h[4]};
        P01 = pkfma(W0h01[0], k0, P01);  v2 Q01 = W0h01[2] * k2;
        P23 = pkfma(W0h23[0], k0, P23);  v2 Q23 = W0h23[2] * k2;
        P01 = pkfma(W0h01[1], k1, P01);  Q01 = pkfma(W0h01[3], k3, Q01);
        P23 = pkfma(W0h23[1], k1, P23);  Q23 = pkfma(W0h23[3], k3, Q23);
        Q01 = pkfma(W0h01[4], k4, Q01);
        Q23 = pkfma(W0h23[4], k4, Q23);
        A01 = P01 + Q01; A23 = P23 + Q23;
    };
    auto matvec1 = [&](const float (&h0)[5], const float (&h1)[5], v2& A01, v2& A23) {
        v2 P01 = BB101, P23 = BB123;
        const v2 g0 = v2{h1[0], h1[0]};
        v2 Q01 = W1b01[0] * g0;
        v2 Q23 = W1b23[0] * g0;
        #pragma unroll
        for (int k = 0; k < 5; ++k) {
            const v2 hk = v2{h0[k], h0[k]};
            P01 = pkfma(W1a01[k], hk, P01);
            P23 = pkfma(W1a23[k], hk, P23);
        }
        #pragma unroll
        for (int k = 1; k < 5; ++k) {
            const v2 gk = v2{h1[k], h1[k]};
            Q01 = pkfma(W1b01[k], gk, Q01);
            Q23 = pkfma(W1b23[k], gk, Q23);
        }
        A01 = P01 + Q01; A23 = P23 + Q23;
    };

    // ---- init: h1(t0-1) = 0; h0(t0) computed and stored ----
    hsh[ww + 204] = 0.0f;
    {
        float z[5] = {0, 0, 0, 0, 0};
        v2 A01, A23;
        matvec0(ldx(t), z, A01, A23);
        const float h0n = cellp(A01, A23, C0);
        hsh[ww] = h0n;                       // same-wave LDS: in-order, no barrier
    }
    float xc = ldx(t + 1);

    // step t: read h0(t), h1(t-1); layer1 -> h1(t) -> store; layer0 -> h0(t+1)
    // -> store; emit out[t-1] from the h1(t-1) regs (deferred head).
    // Same-wave LDS write->read to identical addresses: compiler must keep
    // order (may-alias) and the DS pipe is in-order per wave. No barriers.
    #define STEP(EMIT)                                                         \
    {                                                                          \
        float h0v[5], h1v[5];                                                  \
        {                                                                      \
            const v4 a0 = *(const v4*)&hsh[rw];                                \
            const v4 a1 = *(const v4*)&hsh[rw + 204];                          \
            h0v[0] = a0[0]; h0v[1] = a0[1]; h0v[2] = a0[2]; h0v[3] = a0[3];    \
            h0v[4] = hsh[rw + 4];                                              \
            h1v[0] = a1[0]; h1v[1] = a1[1]; h1v[2] = a1[2]; h1v[3] = a1[3];    \
            h1v[4] = hsh[rw + 204 + 4];                                        \
        }                                                                      \
        v2 A01, A23;                                                           \
        matvec1(h0v, h1v, A01, A23);                                           \
        const float h1n = cellp(A01, A23, C1);                                 \
        hsh[ww + 204] = h1n;                                                   \
        const float xn = ldx(t + 2);                                           \
        matvec0(xc, h0v, A01, A23);                                            \
        const float h0n = cellp(A01, A23, C0);                                 \
        hsh[ww] = h0n;                                                         \
        xc = xn;                                                               \
        if (EMIT) {                                                            \
            float p = vb[0] * h1v[0];                                          \
            p = __builtin_fmaf(vb[1], h1v[1], p);                              \
            p = __builtin_fmaf(vb[2], h1v[2], p);                              \
            p = __builtin_fmaf(vb[3], h1v[3], p);                              \
            p = __builtin_fmaf(vb[4], h1v[4], p);                              \
            const float u = p + bperm(rd5, p);                                 \
            const float S = u + bperm(rd10, u);                                \
            if (q == 0 && (t - 1) < T_TOTAL) out[t - 1] = S + sc;              \
        }                                                                      \
        ++t;                                                                   \
    }

    // ---- warm-up: uniform 24 steps (chunk 0 runs a dummy warm) ----
    for (int i = 0; i < WARM; ++i) STEP(false)

    // ---- chunk 0 exactness: reset state + redo init at t=0 (once, masked) ----
    if (blockIdx.x == 0 && cw == 0) {
        C0 = 0.0f; C1 = 0.0f;
        hsh[ww + 204] = 0.0f;                // h1(-1) = 0
        float z[5] = {0, 0, 0, 0, 0};
        v2 A01, A23;
        matvec0(inp[b], z, A01, A23);        // x(0), zero state
        const float h0n = cellp(A01, A23, C0);
        hsh[ww] = h0n;                       // h0(0)
        xc = inp[4 + b];                     // x(1)
        // t is already 0 for this lane-group
    }

    // ---- pipeline fill: step t=o_begin computes h1(o_begin); no emit
    //      (its emit slot out[o_begin-1] belongs to the previous chunk) ----
    STEP(false)

    // ---- output loop: steps t=o_begin+1..o_begin+CLEN emit out[t-1] ----
    for (int i = 0; i < CLEN; ++i) STEP(true)

    #undef STEP
}

extern "C" void kernel_launch(void* const* d_in, const int* in_sizes, int n_in,
                              void* d_out, int out_size, void* d_ws, size_t ws_size,
                              hipStream_t stream) {
    (void)in_sizes; (void)n_in; (void)d_ws; (void)ws_size; (void)out_size;
    lstm_chunks<<<NCHUNK / 3, 64, 0, stream>>>(
        (const float*)d_in[0],  (const float*)d_in[1],  (const float*)d_in[2],
        (const float*)d_in[3],  (const float*)d_in[4],  (const float*)d_in[5],
        (const float*)d_in[6],  (const float*)d_in[7],  (const float*)d_in[8],
        (const float*)d_in[9],  (const float*)d_in[10], (const float*)d_in[11],
        (const float*)d_in[12], (float*)d_out);
}

// Round 9
// 192.687 us; speedup vs baseline: 1.0745x; 1.0169x over previous
//
#include <hip/hip_runtime.h>

// Problem constants (from reference)
#define T_TOTAL 1000000
#define NCHUNK  9216      // parallel time-chunks -> 3072 blocks = 3 waves/SIMD (proven best)
#define CLEN    109       // 9216*109 = 1,004,544 >= T_TOTAL
#define WARM    24        // warm-up steps (discarded); floor observed at every WARM >= 24

// R23 POST-MORTEM: LDS transport == bperm transport (247 vs 237 cy/chunk-step)
// -> DS-pipe theory FALSIFIED. Surviving model (fits R0/R17/R21/R23 <4%):
//   wall_SIMD/wave-step = VALU_execute (~463cy) + TRANS_execute (+ eps)
//   trans = 14 ops/step (10 exp2 + 4 rcp, 7 per cellp x2) x ~16cy = 224cy
//   -> 687 ~= 712 (R0); 1390 ~= 1440 (R21 STEP2); 706 ~= 741 (R23).
// Trans execute occupies the VALU path at quarter rate; no transport or
// occupancy change touches it. THE LEVER IS TRANS COUNT.
// R24: merged-cell epilogue. The two cellp's per step are independent
// (h1(t), h0(t+1) both consumed only next step):
//   - shared gate rcp:   r8=rcp(P1*P0); r1=r8*P0; r0=r8*P1  (-1 rcp, +3 mul)
//     (P products <= ~21^8 ~ 4e10, safe in f32)
//   - shared output rcp: rr=rcp(E1*E0); h=o(1-eh)*Eother*rr (-1 rcp, +3 mul)
//   - 8 gate exps dependency-parallel -> chain ~1546 -> ~500cy
//   - ping-pong h1A/h1B (R19, proven) -> -5 movs/step
// Trans 14 -> 12: wave-step 712 -> ~675-685 -> predict ~108-114us dispatch.
// Decisive: dur unchanged ~118 -> trans model wrong -> R0 was the ceiling.
// R16 lesson: NEVER use __launch_bounds__ min-waves arg. Grid sets occupancy.

typedef float v2 __attribute__((ext_vector_type(2)));   // -> v_pk_*_f32

#define L2E  1.44269504088896340736f
#define K2   2.88539008177792681472f   // 2*log2(e)

__device__ __forceinline__ float bperm(int addr4, float v) {
    return __int_as_float(__builtin_amdgcn_ds_bpermute(addr4, __float_as_int(v)));
}
__device__ __forceinline__ v2 pkfma(v2 a, v2 b, v2 c) {
    return __builtin_elementwise_fma(a, b, c);
}
__device__ __forceinline__ float ex2(float x) { return __builtin_amdgcn_exp2f(x); }
__device__ __forceinline__ float rcp(float x) { return __builtin_amdgcn_rcpf(x); }

// (64,1): allocator cap 256 VGPR >> ~110-reg live set -> no spills.
__global__ __launch_bounds__(64, 1) void lstm_chunks(
    const float* __restrict__ inp,    // (T,1,4)
    const float* __restrict__ wih0,   // (20,1)
    const float* __restrict__ whh0,   // (20,5)
    const float* __restrict__ bih0,   // (20,)
    const float* __restrict__ bhh0,   // (20,)
    const float* __restrict__ wih1,   // (20,5)
    const float* __restrict__ whh1,   // (20,5)
    const float* __restrict__ bih1,   // (20,)
    const float* __restrict__ bhh1,   // (20,)
    const float* __restrict__ fc1w,   // (10,20)
    const float* __restrict__ fc1b,   // (10,)
    const float* __restrict__ fc2w,   // (1,10)
    const float* __restrict__ fc2b,   // (1,)
    float* __restrict__ out)          // (T,1,1)
{
    const int lane = threadIdx.x & 63;
    int cw = lane / 20; if (cw > 2) cw = 2;  // lane-group 0..2; lanes 60-63 shadow
    int q  = lane - cw * 20; if (q > 19) q = 19;
    const int b = q / 5;                     // batch channel 0..3
    const int j = q % 5;                     // hidden index 0..4
    const int chunk = blockIdx.x * 3 + cw;
    const int base  = cw * 20;

    // ---- cross-lane gather addresses (intra-wave) ----
    int gh[5];
    #pragma unroll
    for (int k = 0; k < 5; ++k) gh[k] = (base + b * 5 + k) * 4;
    const int rd5  = (lane + 5)  * 4;
    const int rd10 = (lane + 10) * 4;

    // ---- packed pre-scaled weights: pairs (i,f)=01, (g,o)=23; rows g*5+j ----
    // scale: i,f,o rows by -log2e; g row by -2log2e (see epilogue).
    v2 W0x01, W0x23, BB001, BB023, BB101, BB123;
    v2 W0h01[5], W0h23[5], W1a01[5], W1a23[5], W1b01[5], W1b23[5];
    {
        const int r0 = j, r1 = 5 + j, r2 = 10 + j, r3 = 15 + j;
        const v2 s01 = v2{-L2E, -L2E};
        const v2 s23 = v2{-K2,  -L2E};
        W0x01 = s01 * v2{wih0[r0], wih0[r1]};
        W0x23 = s23 * v2{wih0[r2], wih0[r3]};
        BB001 = s01 * v2{bih0[r0] + bhh0[r0], bih0[r1] + bhh0[r1]};
        BB023 = s23 * v2{bih0[r2] + bhh0[r2], bih0[r3] + bhh0[r3]};
        BB101 = s01 * v2{bih1[r0] + bhh1[r0], bih1[r1] + bhh1[r1]};
        BB123 = s23 * v2{bih1[r2] + bhh1[r2], bih1[r3] + bhh1[r3]};
        #pragma unroll
        for (int k = 0; k < 5; ++k) {
            W0h01[k] = s01 * v2{whh0[r0 * 5 + k], whh0[r1 * 5 + k]};
            W0h23[k] = s23 * v2{whh0[r2 * 5 + k], whh0[r3 * 5 + k]};
            W1a01[k] = s01 * v2{wih1[r0 * 5 + k], wih1[r1 * 5 + k]};
            W1a23[k] = s23 * v2{wih1[r2 * 5 + k], wih1[r3 * 5 + k]};
            W1b01[k] = s01 * v2{whh1[r0 * 5 + k], whh1[r1 * 5 + k]};
            W1b23[k] = s23 * v2{whh1[r2 * 5 + k], whh1[r3 * 5 + k]};
        }
    }
    // ---- collapsed linear head: out = v . h1cat + s, v = fc2_w @ fc1_w ----
    float vb[5] = {0, 0, 0, 0, 0};
    float sc = fc2b[0];
    #pragma unroll
    for (int m = 0; m < 10; ++m) {
        const float f2 = fc2w[m];
        sc = __builtin_fmaf(f2, fc1b[m], sc);
        #pragma unroll
        for (int k = 0; k < 5; ++k)
            vb[k] = __builtin_fmaf(f2, fc1w[m * 20 + b * 5 + k], vb[k]);
    }

    // ---- chunk time range ----
    const int o_begin = chunk * CLEN;
    const int warm = (chunk == 0) ? 0 : WARM;   // chunk 0 starts exactly from zero state

    // ---- state (C in scaled domain; zero maps to zero) ----
    float C0 = 0.0f, C1 = 0.0f;
    float h0r[5] = {0, 0, 0, 0, 0};   // broadcast of h0(t)
    float h1A[5] = {0, 0, 0, 0, 0};   // broadcast of h1(t-1) [ping]
    float h1B[5] = {0, 0, 0, 0, 0};   //                      [pong]

    auto ldx = [&](int t_) -> float {
        const int tt = (t_ > T_TOTAL - 1) ? (T_TOTAL - 1) : t_;
        return inp[(size_t)tt * 4 + b];
    };

    auto matvec0 = [&](float x, const float (&h)[5], v2& A01, v2& A23) {
        const v2 xx = v2{x, x};
        v2 P01 = pkfma(W0x01, xx, BB001);
        v2 P23 = pkfma(W0x23, xx, BB023);
        const v2 k0 = v2{h[0], h[0]}, k1 = v2{h[1], h[1]};
        const v2 k2 = v2{h[2], h[2]}, k3 = v2{h[3], h[3]};
        const v2 k4 = v2{h[4], h[4]};
        P01 = pkfma(W0h01[0], k0, P01);  v2 Q01 = W0h01[2] * k2;
        P23 = pkfma(W0h23[0], k0, P23);  v2 Q23 = W0h23[2] * k2;
        P01 = pkfma(W0h01[1], k1, P01);  Q01 = pkfma(W0h01[3], k3, Q01);
        P23 = pkfma(W0h23[1], k1, P23);  Q23 = pkfma(W0h23[3], k3, Q23);
        Q01 = pkfma(W0h01[4], k4, Q01);
        Q23 = pkfma(W0h23[4], k4, Q23);
        A01 = P01 + Q01; A23 = P23 + Q23;
    };
    auto matvec1 = [&](const float (&h0)[5], const float (&h1)[5], v2& A01, v2& A23) {
        v2 P01 = BB101, P23 = BB123;
        const v2 g0 = v2{h1[0], h1[0]};
        v2 Q01 = W1b01[0] * g0;
        v2 Q23 = W1b23[0] * g0;
        #pragma unroll
        for (int k = 0; k < 5; ++k) {
            const v2 hk = v2{h0[k], h0[k]};
            P01 = pkfma(W1a01[k], hk, P01);
            P23 = pkfma(W1a23[k], hk, P23);
        }
        #pragma unroll
        for (int k = 1; k < 5; ++k) {
            const v2 gk = v2{h1[k], h1[k]};
            Q01 = pkfma(W1b01[k], gk, Q01);
            Q23 = pkfma(W1b23[k], gk, Q23);
        }
        A01 = P01 + Q01; A23 = P23 + Q23;
    };

    // single-cell epilogue (prologue only; identical math to R12 cellp)
    auto cellp = [&](v2 A01, v2 A23, float& C) -> float {
        const float ei = ex2(A01.x), ef = ex2(A01.y);
        const float eg = ex2(A23.x), eo = ex2(A23.y);
        const float Di = 1.0f + ei, Df = 1.0f + ef, Dg = 1.0f + eg, Do = 1.0f + eo;
        const float p1 = Di * Df, p2 = Dg * Do, p3 = Df * Do;
        const float r  = rcp(p1 * p2);
        const float f  = (Di * p2) * r;
        const float o  = (p1 * Dg) * r;
        const float tg = __builtin_fmaf(K2, eg, -K2);
        C = __builtin_fmaf(f, C, (tg * p3) * r);
        const float eh = ex2(C);
        return (o * (1.0f - eh)) * rcp(1.0f + eh);
    };

    // ---- prologue: layer0 for the first step, broadcast h0 ----
    int t = o_begin - warm;
    {
        v2 A01, A23;
        matvec0(ldx(t), h0r, A01, A23);          // h0r is all zeros here
        const float h0 = cellp(A01, A23, C0);
        #pragma unroll
        for (int k = 0; k < 5; ++k) h0r[k] = bperm(gh[k], h0);
    }
    float xc = ldx(t + 1);

    // merged-cell step: both matvecs (independent: both read OLD h0r/h1),
    // 8 parallel gate exps, shared gate rcp, both C updates, 2 output exps,
    // shared output rcp, both broadcasts back-to-back.
    // Trans: 10 exp2 + 2 rcp = 12 (was 14).
    #define STEP(H1IN, H1OUT, EMIT)                                            \
    {                                                                          \
        v2 A101, A123, A001, A023;                                             \
        matvec1(h0r, H1IN, A101, A123);                                        \
        matvec0(xc, h0r, A001, A023);                                          \
        const float xn = ldx(t + 2);                                           \
        const float e1i = ex2(A101.x), e1f = ex2(A101.y);                      \
        const float e1g = ex2(A123.x), e1o = ex2(A123.y);                      \
        const float e0i = ex2(A001.x), e0f = ex2(A001.y);                      \
        const float e0g = ex2(A023.x), e0o = ex2(A023.y);                      \
        const float D1i = 1.0f + e1i, D1f = 1.0f + e1f;                        \
        const float D1g = 1.0f + e1g, D1o = 1.0f + e1o;                        \
        const float D0i = 1.0f + e0i, D0f = 1.0f + e0f;                        \
        const float D0g = 1.0f + e0g, D0o = 1.0f + e0o;                        \
        const float p11 = D1i * D1f, p12 = D1g * D1o, p13 = D1f * D1o;         \
        const float p01 = D0i * D0f, p02 = D0g * D0o, p03 = D0f * D0o;         \
        const float P1 = p11 * p12, P0 = p01 * p02;                            \
        const float r8 = rcp(P1 * P0);                                         \
        const float r1 = r8 * P0, r0 = r8 * P1;                                \
        const float f1 = (D1i * p12) * r1, o1 = (p11 * D1g) * r1;              \
        const float tg1 = __builtin_fmaf(K2, e1g, -K2);                        \
        C1 = __builtin_fmaf(f1, C1, (tg1 * p13) * r1);                         \
        const float f0 = (D0i * p02) * r0, o0 = (p01 * D0g) * r0;              \
        const float tg0 = __builtin_fmaf(K2, e0g, -K2);                        \
        C0 = __builtin_fmaf(f0, C0, (tg0 * p03) * r0);                         \
        const float eh1 = ex2(C1), eh0 = ex2(C0);                              \
        const float E1 = 1.0f + eh1, E0 = 1.0f + eh0;                          \
        const float rr = rcp(E1 * E0);                                         \
        const float h1 = (o1 * (1.0f - eh1)) * (E0 * rr);                      \
        const float h0 = (o0 * (1.0f - eh0)) * (E1 * rr);                      \
        _Pragma("unroll")                                                      \
        for (int k = 0; k < 5; ++k) H1OUT[k] = bperm(gh[k], h1);               \
        _Pragma("unroll")                                                      \
        for (int k = 0; k < 5; ++k) h0r[k] = bperm(gh[k], h0);                 \
        xc = xn;                                                               \
        if (EMIT) {                                                            \
            float p = vb[0] * H1OUT[0];                                        \
            p = __builtin_fmaf(vb[1], H1OUT[1], p);                            \
            p = __builtin_fmaf(vb[2], H1OUT[2], p);                            \
            p = __builtin_fmaf(vb[3], H1OUT[3], p);                            \
            p = __builtin_fmaf(vb[4], H1OUT[4], p);                            \
            const float u = p + bperm(rd5, p);                                 \
            const float S = u + bperm(rd10, u);                                \
            if (q == 0 && t < T_TOTAL) out[t] = S + sc;                        \
        }                                                                      \
        ++t;                                                                   \
    }

    // ---- warm-up: recurrence only. warm is 0 or 24 (even -> ping-pong
    //      parity preserved); lane-group-divergent trip count exec-masked;
    //      bperms stay within each active 20-lane group. ----
    for (int i = 0; i < warm; i += 2) { STEP(h1A, h1B, false) STEP(h1B, h1A, false) }
    // ---- output loop: 54 pairs + 1 tail = 109 steps ----
    for (int i = 0; i < CLEN - 1; i += 2) { STEP(h1A, h1B, true) STEP(h1B, h1A, true) }
    STEP(h1A, h1B, true)

    #undef STEP
}

extern "C" void kernel_launch(void* const* d_in, const int* in_sizes, int n_in,
                              void* d_out, int out_size, void* d_ws, size_t ws_size,
                              hipStream_t stream) {
    (void)in_sizes; (void)n_in; (void)d_ws; (void)ws_size; (void)out_size;
    lstm_chunks<<<NCHUNK / 3, 64, 0, stream>>>(
        (const float*)d_in[0],  (const float*)d_in[1],  (const float*)d_in[2],
        (const float*)d_in[3],  (const float*)d_in[4],  (const float*)d_in[5],
        (const float*)d_in[6],  (const float*)d_in[7],  (const float*)d_in[8],
        (const float*)d_in[9],  (const float*)d_in[10], (const float*)d_in[11],
        (const float*)d_in[12], (float*)d_out);
}